// Round 6
// baseline (409.872 us; speedup 1.0000x reference)
//
#include <hip/hip_runtime.h>
#include <hip/hip_bf16.h>

// B=4, S=2048, C=1024 attention block, fp32 in/out.
// Barrier-free GEMMs: one wave (64 thr) per block, private 64x64 tile,
// BK=32, double-buffered LDS (4 static arrays, unroll-by-2 -> compile-time
// buffer choice, NO __syncthreads in the K-loop). global_load_lds(16B)
// staging, XOR-chunk swizzle (2-way, free), XCD-aware remap.
// Merged QKV projection (V writes V^T); fp16 scores + softmax; fp32 out.

typedef _Float16 half8 __attribute__((ext_vector_type(8)));
typedef _Float16 half4 __attribute__((ext_vector_type(4)));
typedef float f32x4 __attribute__((ext_vector_type(4)));

#define AS1(p) ((const __attribute__((address_space(1))) void*)(p))
#define AS3(p) ((__attribute__((address_space(3))) void*)(p))

// ---------------- fp32 -> fp16 convert, 3 tensors per launch ----------------
__global__ __launch_bounds__(256) void cvt3_f32_f16(
    const float* __restrict__ s0, const float* __restrict__ s1,
    const float* __restrict__ s2, _Float16* __restrict__ d0,
    _Float16* __restrict__ d1, _Float16* __restrict__ d2, int n) {
    const float* s = blockIdx.y == 0 ? s0 : blockIdx.y == 1 ? s1 : s2;
    _Float16* d = blockIdx.y == 0 ? d0 : blockIdx.y == 1 ? d1 : d2;
    int i = (blockIdx.x * 256 + threadIdx.x) * 8;
    if (i >= n) return;
    float4 a = *(const float4*)(s + i);
    float4 b = *(const float4*)(s + i + 4);
    half8 h;
    h[0] = (_Float16)a.x; h[1] = (_Float16)a.y; h[2] = (_Float16)a.z; h[3] = (_Float16)a.w;
    h[4] = (_Float16)b.x; h[5] = (_Float16)b.y; h[6] = (_Float16)b.z; h[7] = (_Float16)b.w;
    *(half8*)(d + i) = h;
}

// ---------------- barrier-free NT GEMM, 64x64 wave tile, BK=32 --------------
// C[m,n] = scale*sum_k A[m,k]*Bt[n,k] (+bias). One wave per block.
// LDS row = 32 halves (4 x 16B chunks); physical chunk = logical ^ ((row>>1)&3).
// Staging (4 instr per 64x32 tile): lane l -> row u*16+(l>>2), logical chunk
// (l&3)^((l>>3)&3); LDS dest = wave-uniform + lane*16 (HW rule) => row-major.
// Frag read: row i*16+l16, phys chunk quad^((l16>>1)&3) -> 2-way banks (free).
// MODE 0: merged QKV proj (fp16 out + bias, tz==2 writes V^T). MODE 1: fp16
// out with scale (scores). MODE 2: fp32 out (PV).
template <int K, int NX_SH, int RR, int NYT_SH, int MODE>
__global__ __launch_bounds__(64, 2)
void gemm_nt(const _Float16* __restrict__ A, const _Float16* __restrict__ Bt,
             const float* __restrict__ b0, const float* __restrict__ b1,
             const float* __restrict__ b2, void* __restrict__ Cout,
             _Float16* __restrict__ VtOut, int N, float scale,
             long sA, long sB, long sC) {
    __shared__ _Float16 A0[2048] __attribute__((aligned(16)));
    __shared__ _Float16 B0[2048] __attribute__((aligned(16)));
    __shared__ _Float16 A1[2048] __attribute__((aligned(16)));
    __shared__ _Float16 B1[2048] __attribute__((aligned(16)));
    const int l = threadIdx.x;       // 0..63, one wave

    // XCD-aware remap: xcd = lin&7 owns RR contiguous row_ids x all x-tiles.
    const int lin = blockIdx.x;
    const int g = lin & 7;
    const int s = lin >> 3;
    const int xt = s & ((1 << NX_SH) - 1);
    const int row_id = g * RR + (s >> NX_SH);
    const int yt = row_id & ((1 << NYT_SH) - 1);
    const int tz = row_id >> NYT_SH;         // MODE0: tensor id; else batch id
    const int m0 = yt * 64;
    const int n0 = xt * 64;

    const float* bias = nullptr;
    if constexpr (MODE == 0) {
        A += (long)tz * 8388608;             // Xq,Xk,Xv contiguous
        Bt += (long)tz * 1048576;            // Wqh,Wkh,Wvh contiguous
        bias = tz == 0 ? b0 : tz == 1 ? b1 : b2;
    } else {
        A += (long)tz * sA;
        Bt += (long)tz * sB;
    }

    const int larow = l >> 2;                               // 0..15
    const int lchunk = (((l & 3) ^ ((l >> 3) & 3)) << 3);   // logical chunk (halves)
    const int quad = l >> 4;
    const int l16 = l & 15;
    const int rdoff = ((quad ^ ((l16 >> 1) & 3)) << 3);     // phys chunk (halves)

    const _Float16* Ag = A + (long)m0 * K;
    const _Float16* Bg = Bt + (long)n0 * K;

    f32x4 acc[4][4];
#pragma unroll
    for (int i = 0; i < 4; i++)
#pragma unroll
        for (int j = 0; j < 4; j++)
#pragma unroll
            for (int r = 0; r < 4; r++) acc[i][j][r] = 0.0f;

#define STAGE(Ad, Bd, k0)                                                        \
    {                                                                            \
        _Pragma("unroll") for (int u = 0; u < 4; ++u) {                          \
            __builtin_amdgcn_global_load_lds(                                    \
                AS1(Ag + (long)(u * 16 + larow) * K + (k0) + lchunk),            \
                AS3(Ad + u * 512), 16, 0, 0);                                    \
            __builtin_amdgcn_global_load_lds(                                    \
                AS1(Bg + (long)(u * 16 + larow) * K + (k0) + lchunk),            \
                AS3(Bd + u * 512), 16, 0, 0);                                    \
        }                                                                        \
    }

#define COMPUTE(As, Bs)                                                          \
    {                                                                            \
        half8 af[4], bf[4];                                                      \
        _Pragma("unroll") for (int i = 0; i < 4; i++)                            \
            af[i] = *(const half8*)(As + (i * 16 + l16) * 32 + rdoff);           \
        _Pragma("unroll") for (int j = 0; j < 4; j++)                            \
            bf[j] = *(const half8*)(Bs + (j * 16 + l16) * 32 + rdoff);           \
        _Pragma("unroll") for (int i = 0; i < 4; i++)                            \
            _Pragma("unroll") for (int j = 0; j < 4; j++)                        \
                acc[i][j] =                                                      \
                    __builtin_amdgcn_mfma_f32_16x16x32_f16(af[i], bf[j],         \
                                                           acc[i][j], 0, 0, 0); \
    }

    STAGE(A0, B0, 0)
    for (int k0 = 0; k0 < K; k0 += 64) {
        STAGE(A1, B1, k0 + 32)           // k0+32 < K always (K % 64 == 0)
        COMPUTE(A0, B0)
        if (k0 + 64 < K) STAGE(A0, B0, k0 + 64)
        COMPUTE(A1, B1)
    }
#undef STAGE
#undef COMPUTE

    // Epilogue: C/D layout col=lane&15, row=quad*4+reg (m89/m121-128 verified).
#pragma unroll
    for (int i = 0; i < 4; i++) {
        const int row = m0 + i * 16 + quad * 4;
#pragma unroll
        for (int j = 0; j < 4; j++) {
            const int col = n0 + j * 16 + l16;
            if constexpr (MODE == 0) {
                const float badd = bias[col];
                if (tz == 2) {
                    // Vt[b][col][row&2047]; 4 consecutive s-elems (8B store)
                    const long b = row >> 11;
                    const int sl = row & 2047;
                    half4 h;
#pragma unroll
                    for (int r = 0; r < 4; r++) h[r] = (_Float16)(acc[i][j][r] + badd);
                    *(half4*)(VtOut + b * 2097152 + (long)col * 2048 + sl) = h;
                } else {
                    _Float16* o = (_Float16*)Cout + (long)tz * 8388608;
#pragma unroll
                    for (int r = 0; r < 4; r++)
                        o[(long)(row + r) * N + col] = (_Float16)(acc[i][j][r] + badd);
                }
            } else if constexpr (MODE == 1) {
#pragma unroll
                for (int r = 0; r < 4; r++)
                    ((_Float16*)Cout + (long)tz * sC)[(long)(row + r) * N + col] =
                        (_Float16)(acc[i][j][r] * scale);
            } else {
#pragma unroll
                for (int r = 0; r < 4; r++)
                    ((float*)Cout + (long)tz * sC)[(long)(row + r) * N + col] =
                        acc[i][j][r];
            }
        }
    }
}

// ---------------- row softmax: fp16 scores [8192][2048] -> fp16 probs --------
__global__ __launch_bounds__(256) void softmax_f16(const _Float16* __restrict__ S,
                                                   _Float16* __restrict__ P) {
    const long row = blockIdx.x;
    const int t = threadIdx.x;
    const int wave = t >> 6, lane = t & 63;
    half8 h = ((const half8*)(S + row * 2048))[t];
    float v[8];
#pragma unroll
    for (int j = 0; j < 8; j++) v[j] = (float)h[j];
    float m = v[0];
#pragma unroll
    for (int j = 1; j < 8; j++) m = fmaxf(m, v[j]);
#pragma unroll
    for (int off = 32; off > 0; off >>= 1) m = fmaxf(m, __shfl_xor(m, off, 64));
    __shared__ float redm[4], reds[4];
    if (lane == 0) redm[wave] = m;
    __syncthreads();
    m = fmaxf(fmaxf(redm[0], redm[1]), fmaxf(redm[2], redm[3]));
    float sum = 0.0f;
#pragma unroll
    for (int j = 0; j < 8; j++) { v[j] = __expf(v[j] - m); sum += v[j]; }
#pragma unroll
    for (int off = 32; off > 0; off >>= 1) sum += __shfl_xor(sum, off, 64);
    if (lane == 0) reds[wave] = sum;
    __syncthreads();
    sum = (reds[0] + reds[1]) + (reds[2] + reds[3]);
    const float inv = 1.0f / sum;
    half8 o;
#pragma unroll
    for (int j = 0; j < 8; j++) o[j] = (_Float16)(v[j] * inv);
    ((half8*)(P + row * 2048))[t] = o;
}

// ---------------- launch ----------------------------------------------------
extern "C" void kernel_launch(void* const* d_in, const int* in_sizes, int n_in,
                              void* d_out, int out_size, void* d_ws, size_t ws_size,
                              hipStream_t stream) {
    constexpr int B = 4, S = 2048, C = 1024;
    constexpr long XSZ = (long)B * S * C;   // 8388608
    constexpr long WSZ = (long)C * C;       // 1048576

    const float* query = (const float*)d_in[0];
    const float* key   = (const float*)d_in[1];
    const float* value = (const float*)d_in[2];
    const float* Wq = (const float*)d_in[3];
    const float* bq = (const float*)d_in[4];
    const float* Wk = (const float*)d_in[5];
    const float* bk = (const float*)d_in[6];
    const float* Wv = (const float*)d_in[7];
    const float* bv = (const float*)d_in[8];
    float* out = (float*)d_out;
    char* ws = (char*)d_ws;

    // Workspace: [0) Xq,Xk,Xv contiguous (48MB); [50331648) Wqh,Wkh,Wvh (6MB);
    // region reused for fp16 scores after projections. [73400320) Qh,Kh
    // contiguous (reused for attn). [106954752) Vt.  Total 123731968 B.
    _Float16* Xq  = (_Float16*)(ws + 0);
    _Float16* Wqh = (_Float16*)(ws + 3 * XSZ * 2);
    _Float16* scores = (_Float16*)(ws + 0);
    _Float16* Qh  = (_Float16*)(ws + 73400320);
    _Float16* attn = (_Float16*)(ws + 73400320);
    _Float16* Vt  = (_Float16*)(ws + 106954752);
    if (ws_size < 123731968) return;

    // 1) convert inputs + weights to fp16 (contiguous destinations)
    cvt3_f32_f16<<<dim3(XSZ / 2048, 3), 256, 0, stream>>>(
        query, key, value, Xq, Xq + XSZ, Xq + 2 * XSZ, (int)XSZ);
    cvt3_f32_f16<<<dim3(WSZ / 2048, 3), 256, 0, stream>>>(
        Wq, Wk, Wv, Wqh, Wqh + WSZ, Wqh + 2 * WSZ, (int)WSZ);

    // 2) merged projections: per tensor 128 m-tiles x 16 n-tiles, K=1024.
    //    row_ids = 3*128 = 384, RR = 48, grid = 6144 (64-thread blocks).
    gemm_nt<1024, 4, 48, 7, 0><<<6144, 64, 0, stream>>>(
        Xq, Wqh, bq, bk, bv, Qh, Vt, C, 1.0f, 0, 0, 0);

    // 3) scores = Qh @ Kh^T / 32, fp16 out: 32 m x 32 n tiles, z=4 -> 4096.
    //    row_ids = 128, RR = 16.
    gemm_nt<1024, 5, 16, 5, 1><<<4096, 64, 0, stream>>>(
        Qh, Qh + XSZ, nullptr, nullptr, nullptr, scores, nullptr, S, 0.03125f,
        (long)S * C, (long)S * C, (long)S * S);

    // 4) row softmax (fp16 in/out)
    softmax_f16<<<B * S, 256, 0, stream>>>(scores, attn);

    // 5) out = attn @ Vt^T, fp32 out: 32 m x 16 n tiles, z=4 -> 2048.
    //    row_ids = 128, RR = 16.
    gemm_nt<2048, 4, 16, 5, 2><<<2048, 64, 0, stream>>>(
        attn, Vt, nullptr, nullptr, nullptr, out, nullptr, C, 1.0f,
        (long)S * S, (long)C * S, (long)S * C);
}